// Round 1
// baseline (511.270 us; speedup 1.0000x reference)
//
#include <hip/hip_runtime.h>
#include <hip/hip_bf16.h>
#include <math.h>

#define CN 64
#define CG 128
#define CS 64
#define EPSV 1e-5f

__device__ __forceinline__ float4 ld4(const float* p){ return *(const float4*)p; }
__device__ __forceinline__ void st4(float* p, float4 v){ *(float4*)p = v; }

// ---------------- GEMM 1: Yg = g @ Wg, plus per-channel sum/sumsq ----------------
__global__ void __launch_bounds__(256) k_gemm_g(
    const float* __restrict__ g, const float* __restrict__ Wg,
    float* __restrict__ Yg, float* __restrict__ sum_g, float* __restrict__ sumsq_g, int Ng)
{
    __shared__ float Wl[CG*CN];   // 32 KB
    __shared__ float Gl[64*CG];   // 32 KB
    int t = threadIdx.x;
    for (int idx = t; idx < CG*CN/4; idx += 256)
        ((float4*)Wl)[idx] = ((const float4*)Wg)[idx];
    int row0 = blockIdx.x * 64;
    for (int idx = t; idx < 64*CG/4; idx += 256){
        int r = idx >> 5;                       // CG/4 = 32 float4 per row
        float4 v = make_float4(0.f,0.f,0.f,0.f);
        if (row0 + r < Ng) v = ((const float4*)(g + (size_t)(row0+r)*CG))[idx & 31];
        ((float4*)Gl)[idx] = v;
    }
    __syncthreads();
    int c = t & 63, rq = t >> 6;
    float acc[16];
    #pragma unroll
    for (int r=0;r<16;r++) acc[r]=0.f;
    for (int k=0;k<CG;k+=4){
        float w0 = Wl[k*CN+c], w1 = Wl[(k+1)*CN+c], w2 = Wl[(k+2)*CN+c], w3 = Wl[(k+3)*CN+c];
        #pragma unroll
        for (int r=0;r<16;r++){
            float4 g4 = *(const float4*)&Gl[(rq*16+r)*CG + k];
            acc[r] = fmaf(g4.x,w0, fmaf(g4.y,w1, fmaf(g4.z,w2, fmaf(g4.w,w3, acc[r]))));
        }
    }
    float s=0.f,q=0.f;
    #pragma unroll
    for (int r=0;r<16;r++){
        int row = row0 + rq*16 + r;
        if (row < Ng) Yg[(size_t)row*CN + c] = acc[r];
        s += acc[r]; q += acc[r]*acc[r];       // OOB rows are zero-filled -> contribute 0
    }
    __syncthreads();
    float* red = Gl;                            // reuse LDS
    red[rq*64+c] = s; red[256 + rq*64+c] = q;
    __syncthreads();
    if (t < 64){
        float ss = red[t]+red[64+t]+red[128+t]+red[192+t];
        float qq = red[256+t]+red[320+t]+red[384+t]+red[448+t];
        atomicAdd(&sum_g[t], ss); atomicAdd(&sumsq_g[t], qq);
    }
}

// ------------- GEMM 2: Ys = x[down_idx] @ Ws, plus per-channel sum/sumsq -------------
__global__ void __launch_bounds__(256) k_gemm_s(
    const float* __restrict__ x, const int* __restrict__ down_idx, const float* __restrict__ Ws,
    float* __restrict__ Ys, float* __restrict__ sum_s, float* __restrict__ sumsq_s, int Ng)
{
    __shared__ float Wl[CS*CN];   // 16 KB
    __shared__ float Xl[64*CS];   // 16 KB
    int t = threadIdx.x;
    for (int idx = t; idx < CS*CN/4; idx += 256)
        ((float4*)Wl)[idx] = ((const float4*)Ws)[idx];
    int row0 = blockIdx.x * 64;
    for (int idx = t; idx < 64*CS/4; idx += 256){
        int r = idx >> 4;                       // CS/4 = 16 float4 per row
        float4 v = make_float4(0.f,0.f,0.f,0.f);
        int row = row0 + r;
        if (row < Ng){ int sIdx = down_idx[row]; v = ((const float4*)(x + (size_t)sIdx*CS))[idx & 15]; }
        ((float4*)Xl)[idx] = v;
    }
    __syncthreads();
    int c = t & 63, rq = t >> 6;
    float acc[16];
    #pragma unroll
    for (int r=0;r<16;r++) acc[r]=0.f;
    for (int k=0;k<CS;k+=4){
        float w0 = Wl[k*CN+c], w1 = Wl[(k+1)*CN+c], w2 = Wl[(k+2)*CN+c], w3 = Wl[(k+3)*CN+c];
        #pragma unroll
        for (int r=0;r<16;r++){
            float4 g4 = *(const float4*)&Xl[(rq*16+r)*CS + k];
            acc[r] = fmaf(g4.x,w0, fmaf(g4.y,w1, fmaf(g4.z,w2, fmaf(g4.w,w3, acc[r]))));
        }
    }
    float s=0.f,q=0.f;
    #pragma unroll
    for (int r=0;r<16;r++){
        int row = row0 + rq*16 + r;
        if (row < Ng) Ys[(size_t)row*CN + c] = acc[r];
        s += acc[r]; q += acc[r]*acc[r];
    }
    __syncthreads();
    float* red = Xl;
    red[rq*64+c] = s; red[256 + rq*64+c] = q;
    __syncthreads();
    if (t < 64){
        float ss = red[t]+red[64+t]+red[128+t]+red[192+t];
        float qq = red[256+t]+red[320+t]+red[384+t]+red[448+t];
        atomicAdd(&sum_s[t], ss); atomicAdd(&sumsq_s[t], qq);
    }
}

__device__ __forceinline__ void bnparams(float4 s, float4 q, float4 gam, float4 bet,
                                         float invN, float4& scl, float4& sft)
{
    float mux = s.x*invN, muy = s.y*invN, muz = s.z*invN, muw = s.w*invN;
    float vx = q.x*invN - mux*mux, vy = q.y*invN - muy*muy;
    float vz = q.z*invN - muz*muz, vw = q.w*invN - muw*muw;
    scl = make_float4(gam.x*rsqrtf(vx+EPSV), gam.y*rsqrtf(vy+EPSV),
                      gam.z*rsqrtf(vz+EPSV), gam.w*rsqrtf(vw+EPSV));
    sft = make_float4(bet.x - mux*scl.x, bet.y - muy*scl.y,
                      bet.z - muz*scl.z, bet.w - muw*scl.w);
}

// --------- fuse: w[i] = relu(relu(BN(Yg)) + relu(BN(Ys))) @ Wc, plus w sum/sumsq ---------
__global__ void __launch_bounds__(256) k_fuse(
    const float* __restrict__ Yg, const float* __restrict__ Ys,
    const float* __restrict__ stats,
    const float* __restrict__ gamma_g, const float* __restrict__ beta_g,
    const float* __restrict__ gamma_s, const float* __restrict__ beta_s,
    const float* __restrict__ Wc,
    float* __restrict__ w, float* __restrict__ sum_w, float* __restrict__ sumsq_w, int Ng)
{
    int t = threadIdx.x; int l = t & 15; int r = t >> 4;
    int i = blockIdx.x*16 + r;
    int c4 = l*4;
    float invN = 1.0f/(float)Ng;
    float4 sclg, sftg, scls, sfts;
    bnparams(ld4(stats + c4),       ld4(stats + 64 + c4),  ld4(gamma_g + c4), ld4(beta_g + c4), invN, sclg, sftg);
    bnparams(ld4(stats + 128 + c4), ld4(stats + 192 + c4), ld4(gamma_s + c4), ld4(beta_s + c4), invN, scls, sfts);
    float partial = 0.f;
    if (i < Ng){
        float4 a = ld4(Yg + (size_t)i*CN + c4);
        float4 b = ld4(Ys + (size_t)i*CN + c4);
        float ax = fmaxf(0.f, fmaf(a.x, sclg.x, sftg.x));
        float ay = fmaxf(0.f, fmaf(a.y, sclg.y, sftg.y));
        float az = fmaxf(0.f, fmaf(a.z, sclg.z, sftg.z));
        float aw = fmaxf(0.f, fmaf(a.w, sclg.w, sftg.w));
        float bx = fmaxf(0.f, fmaf(b.x, scls.x, sfts.x));
        float by = fmaxf(0.f, fmaf(b.y, scls.y, sfts.y));
        float bz = fmaxf(0.f, fmaf(b.z, scls.z, sfts.z));
        float bw = fmaxf(0.f, fmaf(b.w, scls.w, sfts.w));
        float sx = fmaxf(0.f, ax+bx), sy = fmaxf(0.f, ay+by);
        float sz = fmaxf(0.f, az+bz), sw = fmaxf(0.f, aw+bw);
        float4 wc = ld4(Wc + c4);
        partial = sx*wc.x + sy*wc.y + sz*wc.z + sw*wc.w;
    }
    partial += __shfl_xor(partial, 1);
    partial += __shfl_xor(partial, 2);
    partial += __shfl_xor(partial, 4);
    partial += __shfl_xor(partial, 8);
    __shared__ float red[32];
    if (l == 0){
        if (i < Ng) w[i] = partial;
        red[r] = (i < Ng) ? partial : 0.f;
        red[16+r] = (i < Ng) ? partial*partial : 0.f;
    }
    __syncthreads();
    if (t == 0){
        float s2=0.f,q2=0.f;
        #pragma unroll
        for (int j2=0;j2<16;j2++){ s2+=red[j2]; q2+=red[16+j2]; }
        atomicAdd(sum_w, s2); atomicAdd(sumsq_w, q2);
    }
}

// --------- att[i] = sigmoid(BN_scalar(w[i])) ---------
__global__ void __launch_bounds__(256) k_att(
    const float* __restrict__ w, const float* __restrict__ stats,
    const float* __restrict__ gamma_c, const float* __restrict__ beta_c,
    float* __restrict__ att, int Ng)
{
    int i = blockIdx.x*256 + threadIdx.x;
    if (i >= Ng) return;
    float invN = 1.0f/(float)Ng;
    float mu = stats[256]*invN;
    float var = stats[257]*invN - mu*mu;
    float sc = gamma_c[0]*rsqrtf(var+EPSV);
    float sh = beta_c[0] - mu*sc;
    float z = fmaf(sc, w[i], sh);
    att[i] = 1.0f/(1.0f+expf(-z));
}

// --------- scalar scatter: A[k][j] += att[pairs_in[k,p]] ---------
__global__ void __launch_bounds__(256) k_scatter(
    const int* __restrict__ pin, const int* __restrict__ pout,
    const float* __restrict__ att, float* __restrict__ A, int P, int Nx)
{
    int p = blockIdx.x*256 + threadIdx.x;
    int k = blockIdx.y;
    if (p >= P) return;
    size_t o = (size_t)k*P + p;
    int i = pin[o]; int j = pout[o];
    atomicAdd(&A[(size_t)k*Nx + j], att[i]);
}

// --------- final: out[j,:] = x[j,:] * (b_inv + sum_k A[k][j] * W_inv[k,:]) ---------
__global__ void __launch_bounds__(256) k_final(
    const float* __restrict__ x, const float* __restrict__ A,
    const float* __restrict__ Winv, const float* __restrict__ binv,
    float* __restrict__ out, int Nx, int K)
{
    __shared__ float Wl[32*CS];
    __shared__ float bl[CS];
    int t = threadIdx.x;
    for (int idx = t; idx < K*CS; idx += 256) Wl[idx] = Winv[idx];
    if (t < CS) bl[t] = binv[t];
    __syncthreads();
    int l = t & 15, r = t >> 4;
    int j = blockIdx.x*16 + r;
    if (j >= Nx) return;
    int c4 = l*4;
    float4 up = ld4(bl + c4);
    for (int k=0;k<K;k++){
        float a = A[(size_t)k*Nx + j];
        float4 wv = *(const float4*)&Wl[k*CS + c4];
        up.x = fmaf(a, wv.x, up.x); up.y = fmaf(a, wv.y, up.y);
        up.z = fmaf(a, wv.z, up.z); up.w = fmaf(a, wv.w, up.w);
    }
    float4 xv = ld4(x + (size_t)j*CS + c4);
    st4(out + (size_t)j*CS + c4, make_float4(xv.x*up.x, xv.y*up.y, xv.z*up.z, xv.w*up.w));
}

extern "C" void kernel_launch(void* const* d_in, const int* in_sizes, int n_in,
                              void* d_out, int out_size, void* d_ws, size_t ws_size,
                              hipStream_t stream)
{
    const float* g        = (const float*)d_in[0];
    const float* x        = (const float*)d_in[1];
    const int*   down_idx = (const int*)d_in[2];
    const int*   pin      = (const int*)d_in[3];
    const int*   pout     = (const int*)d_in[4];
    const float* Wg       = (const float*)d_in[5];
    const float* Ws       = (const float*)d_in[6];
    const float* Wc       = (const float*)d_in[7];
    const float* Winv     = (const float*)d_in[8];
    const float* binv     = (const float*)d_in[9];
    const float* gamma_g  = (const float*)d_in[10];
    const float* beta_g   = (const float*)d_in[11];
    const float* gamma_s  = (const float*)d_in[12];
    const float* beta_s   = (const float*)d_in[13];
    const float* gamma_c  = (const float*)d_in[14];
    const float* beta_c   = (const float*)d_in[15];

    int Ng = in_sizes[0] / CG;       // 60000
    int Nx = in_sizes[1] / CS;       // 200000
    int K  = in_sizes[8] / CS;       // 27
    int P  = in_sizes[3] / K;        // 100000

    float* ws = (float*)d_ws;
    size_t offA     = 0;
    size_t offStats = (size_t)K * Nx;         // A: K*Nx floats
    size_t offYg    = offStats + 512;         // stats: 512 floats
    size_t offYs    = offYg + (size_t)Ng*CN;
    size_t offW     = offYs + (size_t)Ng*CN;
    size_t offAtt   = offW + (size_t)Ng;

    float* A     = ws + offA;
    float* stats = ws + offStats;
    float* Yg    = ws + offYg;
    float* Ys    = ws + offYs;
    float* wbuf  = ws + offW;
    float* att   = ws + offAtt;

    // zero A + stat accumulators (ws is poisoned 0xAA before every call)
    hipMemsetAsync(A, 0, (offStats + 512) * sizeof(float), stream);

    int gb = (Ng + 63) / 64;
    k_gemm_g<<<gb, 256, 0, stream>>>(g, Wg, Yg, stats+0, stats+64, Ng);
    k_gemm_s<<<gb, 256, 0, stream>>>(x, down_idx, Ws, Ys, stats+128, stats+192, Ng);
    k_fuse<<<(Ng+15)/16, 256, 0, stream>>>(Yg, Ys, stats, gamma_g, beta_g,
                                           gamma_s, beta_s, Wc, wbuf,
                                           stats+256, stats+257, Ng);
    k_att<<<(Ng+255)/256, 256, 0, stream>>>(wbuf, stats, gamma_c, beta_c, att, Ng);
    dim3 sgrid((P+255)/256, K);
    k_scatter<<<sgrid, 256, 0, stream>>>(pin, pout, att, A, P, Nx);
    k_final<<<(Nx+15)/16, 256, 0, stream>>>(x, A, Winv, binv, (float*)d_out, Nx, K);
}

// Round 2
// 506.824 us; speedup vs baseline: 1.0088x; 1.0088x over previous
//
#include <hip/hip_runtime.h>
#include <hip/hip_bf16.h>
#include <math.h>

#define CN 64
#define CG 128
#define CS 64
#define EPSV 1e-5f
#define KC 9          // k-slices per scatter thread

__device__ __forceinline__ float4 ld4(const float* p){ return *(const float4*)p; }
__device__ __forceinline__ void st4(float* p, float4 v){ *(float4*)p = v; }

// ---------------- GEMM: Y = X[gather?] @ W, plus per-channel sum/sumsq ----------------
// 64-row x 64-col tile, 4x4 register blocking per thread (256 threads).
// K staged in 64-wide chunks: Xl[64][68] (padded stride 68 -> 2-way-max bank aliasing, free).
template<int CK, bool GATHER>
__global__ void __launch_bounds__(256) k_gemm(
    const float* __restrict__ X, const int* __restrict__ gidx,
    const float* __restrict__ W,
    float* __restrict__ Y, float* __restrict__ sum, float* __restrict__ sumsq, int Ng)
{
    __shared__ float Wl[CK*CN];      // 32 KB (CK=128) or 16 KB (CK=64)
    __shared__ float Xl[64*68];      // 17.4 KB, stride 68 floats
    int t = threadIdx.x;
    for (int idx = t; idx < CK*CN/4; idx += 256)
        ((float4*)Wl)[idx] = ((const float4*)W)[idx];

    int row0 = blockIdx.x * 64;
    int cg = t & 15, rg = t >> 4;
    int c0 = cg*4, r0 = rg*4;
    float4 acc[4];
    #pragma unroll
    for (int rr=0;rr<4;rr++) acc[rr] = make_float4(0.f,0.f,0.f,0.f);

    for (int kc = 0; kc < CK; kc += 64){
        // stage 64 rows x 64 k-cols
        for (int idx = t; idx < 64*16; idx += 256){
            int r = idx >> 4;           // 16 float4 per row
            int c4 = idx & 15;
            float4 v = make_float4(0.f,0.f,0.f,0.f);
            int row = row0 + r;
            if (row < Ng){
                int src = GATHER ? gidx[row] : row;
                v = ((const float4*)(X + (size_t)src*CK + kc))[c4];
            }
            *(float4*)&Xl[r*68 + c4*4] = v;
        }
        __syncthreads();
        for (int k = 0; k < 64; k += 4){
            float4 w0 = ld4(&Wl[(kc+k+0)*CN + c0]);
            float4 w1 = ld4(&Wl[(kc+k+1)*CN + c0]);
            float4 w2 = ld4(&Wl[(kc+k+2)*CN + c0]);
            float4 w3 = ld4(&Wl[(kc+k+3)*CN + c0]);
            #pragma unroll
            for (int rr=0;rr<4;rr++){
                float4 xv = ld4(&Xl[(r0+rr)*68 + k]);
                acc[rr].x = fmaf(xv.x,w0.x, fmaf(xv.y,w1.x, fmaf(xv.z,w2.x, fmaf(xv.w,w3.x, acc[rr].x))));
                acc[rr].y = fmaf(xv.x,w0.y, fmaf(xv.y,w1.y, fmaf(xv.z,w2.y, fmaf(xv.w,w3.y, acc[rr].y))));
                acc[rr].z = fmaf(xv.x,w0.z, fmaf(xv.y,w1.z, fmaf(xv.z,w2.z, fmaf(xv.w,w3.z, acc[rr].z))));
                acc[rr].w = fmaf(xv.x,w0.w, fmaf(xv.y,w1.w, fmaf(xv.z,w2.w, fmaf(xv.w,w3.w, acc[rr].w))));
            }
        }
        __syncthreads();
    }

    float4 s4 = make_float4(0.f,0.f,0.f,0.f), q4 = make_float4(0.f,0.f,0.f,0.f);
    #pragma unroll
    for (int rr=0;rr<4;rr++){
        int row = row0 + r0 + rr;
        if (row < Ng) st4(Y + (size_t)row*CN + c0, acc[rr]);
        // OOB rows got zero-filled inputs -> acc==0 -> contribute 0 to sums
        s4.x += acc[rr].x; s4.y += acc[rr].y; s4.z += acc[rr].z; s4.w += acc[rr].w;
        q4.x += acc[rr].x*acc[rr].x; q4.y += acc[rr].y*acc[rr].y;
        q4.z += acc[rr].z*acc[rr].z; q4.w += acc[rr].w*acc[rr].w;
    }
    // block reduction over the 16 row-groups
    float* red = Xl;                 // reuse (needs 2*16*64 floats = 8 KB)
    st4(red + rg*64 + c0, s4);
    st4(red + 1024 + rg*64 + c0, q4);
    __syncthreads();
    if (t < 64){
        float ss = 0.f, qq = 0.f;
        #pragma unroll
        for (int r=0;r<16;r++){ ss += red[r*64 + t]; qq += red[1024 + r*64 + t]; }
        atomicAdd(&sum[t], ss); atomicAdd(&sumsq[t], qq);
    }
}

__device__ __forceinline__ void bnparams(float4 s, float4 q, float4 gam, float4 bet,
                                         float invN, float4& scl, float4& sft)
{
    float mux = s.x*invN, muy = s.y*invN, muz = s.z*invN, muw = s.w*invN;
    float vx = q.x*invN - mux*mux, vy = q.y*invN - muy*muy;
    float vz = q.z*invN - muz*muz, vw = q.w*invN - muw*muw;
    scl = make_float4(gam.x*rsqrtf(vx+EPSV), gam.y*rsqrtf(vy+EPSV),
                      gam.z*rsqrtf(vz+EPSV), gam.w*rsqrtf(vw+EPSV));
    sft = make_float4(bet.x - mux*scl.x, bet.y - muy*scl.y,
                      bet.z - muz*scl.z, bet.w - muw*scl.w);
}

// --------- fuse: w[i] = relu(relu(BN(Yg)) + relu(BN(Ys))) @ Wc, plus w sum/sumsq ---------
__global__ void __launch_bounds__(256) k_fuse(
    const float* __restrict__ Yg, const float* __restrict__ Ys,
    const float* __restrict__ stats,
    const float* __restrict__ gamma_g, const float* __restrict__ beta_g,
    const float* __restrict__ gamma_s, const float* __restrict__ beta_s,
    const float* __restrict__ Wc,
    float* __restrict__ w, float* __restrict__ sum_w, float* __restrict__ sumsq_w, int Ng)
{
    int t = threadIdx.x; int l = t & 15; int r = t >> 4;
    int i = blockIdx.x*16 + r;
    int c4 = l*4;
    float invN = 1.0f/(float)Ng;
    float4 sclg, sftg, scls, sfts;
    bnparams(ld4(stats + c4),       ld4(stats + 64 + c4),  ld4(gamma_g + c4), ld4(beta_g + c4), invN, sclg, sftg);
    bnparams(ld4(stats + 128 + c4), ld4(stats + 192 + c4), ld4(gamma_s + c4), ld4(beta_s + c4), invN, scls, sfts);
    float partial = 0.f;
    if (i < Ng){
        float4 a = ld4(Yg + (size_t)i*CN + c4);
        float4 b = ld4(Ys + (size_t)i*CN + c4);
        float ax = fmaxf(0.f, fmaf(a.x, sclg.x, sftg.x));
        float ay = fmaxf(0.f, fmaf(a.y, sclg.y, sftg.y));
        float az = fmaxf(0.f, fmaf(a.z, sclg.z, sftg.z));
        float aw = fmaxf(0.f, fmaf(a.w, sclg.w, sftg.w));
        float bx = fmaxf(0.f, fmaf(b.x, scls.x, sfts.x));
        float by = fmaxf(0.f, fmaf(b.y, scls.y, sfts.y));
        float bz = fmaxf(0.f, fmaf(b.z, scls.z, sfts.z));
        float bw = fmaxf(0.f, fmaf(b.w, scls.w, sfts.w));
        float sx = fmaxf(0.f, ax+bx), sy = fmaxf(0.f, ay+by);
        float sz = fmaxf(0.f, az+bz), sw = fmaxf(0.f, aw+bw);
        float4 wc = ld4(Wc + c4);
        partial = sx*wc.x + sy*wc.y + sz*wc.z + sw*wc.w;
    }
    partial += __shfl_xor(partial, 1);
    partial += __shfl_xor(partial, 2);
    partial += __shfl_xor(partial, 4);
    partial += __shfl_xor(partial, 8);
    __shared__ float red[32];
    if (l == 0){
        if (i < Ng) w[i] = partial;
        red[r] = (i < Ng) ? partial : 0.f;
        red[16+r] = (i < Ng) ? partial*partial : 0.f;
    }
    __syncthreads();
    if (t == 0){
        float s2=0.f,q2=0.f;
        #pragma unroll
        for (int j2=0;j2<16;j2++){ s2+=red[j2]; q2+=red[16+j2]; }
        atomicAdd(sum_w, s2); atomicAdd(sumsq_w, q2);
    }
}

// --------- att[i] = sigmoid(BN_scalar(w[i])) ---------
__global__ void __launch_bounds__(256) k_att(
    const float* __restrict__ w, const float* __restrict__ stats,
    const float* __restrict__ gamma_c, const float* __restrict__ beta_c,
    float* __restrict__ att, int Ng)
{
    int i = blockIdx.x*256 + threadIdx.x;
    if (i >= Ng) return;
    float invN = 1.0f/(float)Ng;
    float mu = stats[256]*invN;
    float var = stats[257]*invN - mu*mu;
    float sc = gamma_c[0]*rsqrtf(var+EPSV);
    float sh = beta_c[0] - mu*sc;
    float z = fmaf(sc, w[i], sh);
    att[i] = 1.0f/(1.0f+expf(-z));
}

// --------- scalar scatter: A[k][j] += att[pairs_in[k,p]], KC slices per thread ---------
__global__ void __launch_bounds__(256) k_scatter(
    const int* __restrict__ pin, const int* __restrict__ pout,
    const float* __restrict__ att, float* __restrict__ A, int P, int Nx, int K)
{
    int p = blockIdx.x*256 + threadIdx.x;
    int k0 = blockIdx.y * KC;
    if (p >= P) return;
    int ii[KC], jj[KC];
    #pragma unroll
    for (int u=0;u<KC;u++){
        if (k0+u < K){
            size_t o = (size_t)(k0+u)*P + p;
            ii[u] = pin[o]; jj[u] = pout[o];
        } else { ii[u] = 0; jj[u] = -1; }
    }
    float av[KC];
    #pragma unroll
    for (int u=0;u<KC;u++) av[u] = att[ii[u]];
    #pragma unroll
    for (int u=0;u<KC;u++)
        if (jj[u] >= 0) atomicAdd(&A[(size_t)(k0+u)*Nx + jj[u]], av[u]);
}

// --------- final: out[j,:] = x[j,:] * (b_inv + sum_k A[k][j] * W_inv[k,:]) ---------
__global__ void __launch_bounds__(256) k_final(
    const float* __restrict__ x, const float* __restrict__ A,
    const float* __restrict__ Winv, const float* __restrict__ binv,
    float* __restrict__ out, int Nx, int K)
{
    __shared__ float Wl[32*CS];
    __shared__ float bl[CS];
    int t = threadIdx.x;
    for (int idx = t; idx < K*CS; idx += 256) Wl[idx] = Winv[idx];
    if (t < CS) bl[t] = binv[t];
    __syncthreads();
    int l = t & 15, r = t >> 4;
    int j = blockIdx.x*16 + r;
    if (j >= Nx) return;
    int c4 = l*4;
    float4 up = ld4(bl + c4);
    for (int k=0;k<K;k++){
        float a = A[(size_t)k*Nx + j];
        float4 wv = *(const float4*)&Wl[k*CS + c4];
        up.x = fmaf(a, wv.x, up.x); up.y = fmaf(a, wv.y, up.y);
        up.z = fmaf(a, wv.z, up.z); up.w = fmaf(a, wv.w, up.w);
    }
    float4 xv = ld4(x + (size_t)j*CS + c4);
    st4(out + (size_t)j*CS + c4, make_float4(xv.x*up.x, xv.y*up.y, xv.z*up.z, xv.w*up.w));
}

extern "C" void kernel_launch(void* const* d_in, const int* in_sizes, int n_in,
                              void* d_out, int out_size, void* d_ws, size_t ws_size,
                              hipStream_t stream)
{
    const float* g        = (const float*)d_in[0];
    const float* x        = (const float*)d_in[1];
    const int*   down_idx = (const int*)d_in[2];
    const int*   pin      = (const int*)d_in[3];
    const int*   pout     = (const int*)d_in[4];
    const float* Wg       = (const float*)d_in[5];
    const float* Ws       = (const float*)d_in[6];
    const float* Wc       = (const float*)d_in[7];
    const float* Winv     = (const float*)d_in[8];
    const float* binv     = (const float*)d_in[9];
    const float* gamma_g  = (const float*)d_in[10];
    const float* beta_g   = (const float*)d_in[11];
    const float* gamma_s  = (const float*)d_in[12];
    const float* beta_s   = (const float*)d_in[13];
    const float* gamma_c  = (const float*)d_in[14];
    const float* beta_c   = (const float*)d_in[15];

    int Ng = in_sizes[0] / CG;       // 60000
    int Nx = in_sizes[1] / CS;       // 200000
    int K  = in_sizes[8] / CS;       // 27
    int P  = in_sizes[3] / K;        // 100000

    float* ws = (float*)d_ws;
    size_t offA     = 0;
    size_t offStats = (size_t)K * Nx;         // A: K*Nx floats
    size_t offYg    = offStats + 512;         // stats: 512 floats
    size_t offYs    = offYg + (size_t)Ng*CN;
    size_t offW     = offYs + (size_t)Ng*CN;
    size_t offAtt   = offW + (size_t)Ng;

    float* A     = ws + offA;
    float* stats = ws + offStats;
    float* Yg    = ws + offYg;
    float* Ys    = ws + offYs;
    float* wbuf  = ws + offW;
    float* att   = ws + offAtt;

    // zero A + stat accumulators (ws is poisoned 0xAA before every call)
    hipMemsetAsync(A, 0, (offStats + 512) * sizeof(float), stream);

    int gb = (Ng + 63) / 64;
    k_gemm<CG,false><<<gb, 256, 0, stream>>>(g, nullptr, Wg, Yg, stats+0, stats+64, Ng);
    k_gemm<CS,true ><<<gb, 256, 0, stream>>>(x, down_idx, Ws, Ys, stats+128, stats+192, Ng);
    k_fuse<<<(Ng+15)/16, 256, 0, stream>>>(Yg, Ys, stats, gamma_g, beta_g,
                                           gamma_s, beta_s, Wc, wbuf,
                                           stats+256, stats+257, Ng);
    k_att<<<(Ng+255)/256, 256, 0, stream>>>(wbuf, stats, gamma_c, beta_c, att, Ng);
    dim3 sgrid((P+255)/256, (K + KC - 1)/KC);
    k_scatter<<<sgrid, 256, 0, stream>>>(pin, pout, att, A, P, Nx, K);
    k_final<<<(Nx+15)/16, 256, 0, stream>>>(x, A, Winv, binv, (float*)d_out, Nx, K);
}

// Round 3
// 475.800 us; speedup vs baseline: 1.0745x; 1.0652x over previous
//
#include <hip/hip_runtime.h>
#include <hip/hip_bf16.h>
#include <math.h>

#define CN 64
#define CG 128
#define CS 64
#define EPSV 1e-5f
#define ASTRIDE 28   // A row stride (27 taps + 1 pad, 16B-aligned)

__device__ __forceinline__ float4 ld4(const float* p){ return *(const float4*)p; }
__device__ __forceinline__ void st4(float* p, float4 v){ *(float4*)p = v; }

// ---------------- GEMM: Y = X[gather?] @ W, plus per-channel sum/sumsq ----------------
template<int CK, bool GATHER>
__global__ void __launch_bounds__(256) k_gemm(
    const float* __restrict__ X, const int* __restrict__ gidx,
    const float* __restrict__ W,
    float* __restrict__ Y, float* __restrict__ sum, float* __restrict__ sumsq, int Ng)
{
    __shared__ float Wl[CK*CN];      // 32 KB (CK=128) or 16 KB (CK=64)
    __shared__ float Xl[64*68];      // 17.4 KB, stride 68 floats
    int t = threadIdx.x;
    for (int idx = t; idx < CK*CN/4; idx += 256)
        ((float4*)Wl)[idx] = ((const float4*)W)[idx];

    int row0 = blockIdx.x * 64;
    int cg = t & 15, rg = t >> 4;
    int c0 = cg*4, r0 = rg*4;
    float4 acc[4];
    #pragma unroll
    for (int rr=0;rr<4;rr++) acc[rr] = make_float4(0.f,0.f,0.f,0.f);

    for (int kc = 0; kc < CK; kc += 64){
        for (int idx = t; idx < 64*16; idx += 256){
            int r = idx >> 4;
            int c4 = idx & 15;
            float4 v = make_float4(0.f,0.f,0.f,0.f);
            int row = row0 + r;
            if (row < Ng){
                int src = GATHER ? gidx[row] : row;
                v = ((const float4*)(X + (size_t)src*CK + kc))[c4];
            }
            *(float4*)&Xl[r*68 + c4*4] = v;
        }
        __syncthreads();
        for (int k = 0; k < 64; k += 4){
            float4 w0 = ld4(&Wl[(kc+k+0)*CN + c0]);
            float4 w1 = ld4(&Wl[(kc+k+1)*CN + c0]);
            float4 w2 = ld4(&Wl[(kc+k+2)*CN + c0]);
            float4 w3 = ld4(&Wl[(kc+k+3)*CN + c0]);
            #pragma unroll
            for (int rr=0;rr<4;rr++){
                float4 xv = ld4(&Xl[(r0+rr)*68 + k]);
                acc[rr].x = fmaf(xv.x,w0.x, fmaf(xv.y,w1.x, fmaf(xv.z,w2.x, fmaf(xv.w,w3.x, acc[rr].x))));
                acc[rr].y = fmaf(xv.x,w0.y, fmaf(xv.y,w1.y, fmaf(xv.z,w2.y, fmaf(xv.w,w3.y, acc[rr].y))));
                acc[rr].z = fmaf(xv.x,w0.z, fmaf(xv.y,w1.z, fmaf(xv.z,w2.z, fmaf(xv.w,w3.z, acc[rr].z))));
                acc[rr].w = fmaf(xv.x,w0.w, fmaf(xv.y,w1.w, fmaf(xv.z,w2.w, fmaf(xv.w,w3.w, acc[rr].w))));
            }
        }
        __syncthreads();
    }

    float4 s4 = make_float4(0.f,0.f,0.f,0.f), q4 = make_float4(0.f,0.f,0.f,0.f);
    #pragma unroll
    for (int rr=0;rr<4;rr++){
        int row = row0 + r0 + rr;
        if (row < Ng) st4(Y + (size_t)row*CN + c0, acc[rr]);
        s4.x += acc[rr].x; s4.y += acc[rr].y; s4.z += acc[rr].z; s4.w += acc[rr].w;
        q4.x += acc[rr].x*acc[rr].x; q4.y += acc[rr].y*acc[rr].y;
        q4.z += acc[rr].z*acc[rr].z; q4.w += acc[rr].w*acc[rr].w;
    }
    float* red = Xl;
    __syncthreads();
    st4(red + rg*64 + c0, s4);
    st4(red + 1024 + rg*64 + c0, q4);
    __syncthreads();
    if (t < 64){
        float ss = 0.f, qq = 0.f;
        #pragma unroll
        for (int r=0;r<16;r++){ ss += red[r*64 + t]; qq += red[1024 + r*64 + t]; }
        atomicAdd(&sum[t], ss); atomicAdd(&sumsq[t], qq);
    }
}

__device__ __forceinline__ void bnparams(float4 s, float4 q, float4 gam, float4 bet,
                                         float invN, float4& scl, float4& sft)
{
    float mux = s.x*invN, muy = s.y*invN, muz = s.z*invN, muw = s.w*invN;
    float vx = q.x*invN - mux*mux, vy = q.y*invN - muy*muy;
    float vz = q.z*invN - muz*muz, vw = q.w*invN - muw*muw;
    scl = make_float4(gam.x*rsqrtf(vx+EPSV), gam.y*rsqrtf(vy+EPSV),
                      gam.z*rsqrtf(vz+EPSV), gam.w*rsqrtf(vw+EPSV));
    sft = make_float4(bet.x - mux*scl.x, bet.y - muy*scl.y,
                      bet.z - muz*scl.z, bet.w - muw*scl.w);
}

// --------- fuse: w[i] = relu(relu(BN(Yg)) + relu(BN(Ys))) @ Wc, plus w sum/sumsq ---------
__global__ void __launch_bounds__(256) k_fuse(
    const float* __restrict__ Yg, const float* __restrict__ Ys,
    const float* __restrict__ stats,
    const float* __restrict__ gamma_g, const float* __restrict__ beta_g,
    const float* __restrict__ gamma_s, const float* __restrict__ beta_s,
    const float* __restrict__ Wc,
    float* __restrict__ w, float* __restrict__ sum_w, float* __restrict__ sumsq_w, int Ng)
{
    int t = threadIdx.x; int l = t & 15; int r = t >> 4;
    int i = blockIdx.x*16 + r;
    int c4 = l*4;
    float invN = 1.0f/(float)Ng;
    float4 sclg, sftg, scls, sfts;
    bnparams(ld4(stats + c4),       ld4(stats + 64 + c4),  ld4(gamma_g + c4), ld4(beta_g + c4), invN, sclg, sftg);
    bnparams(ld4(stats + 128 + c4), ld4(stats + 192 + c4), ld4(gamma_s + c4), ld4(beta_s + c4), invN, scls, sfts);
    float partial = 0.f;
    if (i < Ng){
        float4 a = ld4(Yg + (size_t)i*CN + c4);
        float4 b = ld4(Ys + (size_t)i*CN + c4);
        float ax = fmaxf(0.f, fmaf(a.x, sclg.x, sftg.x));
        float ay = fmaxf(0.f, fmaf(a.y, sclg.y, sftg.y));
        float az = fmaxf(0.f, fmaf(a.z, sclg.z, sftg.z));
        float aw = fmaxf(0.f, fmaf(a.w, sclg.w, sftg.w));
        float bx = fmaxf(0.f, fmaf(b.x, scls.x, sfts.x));
        float by = fmaxf(0.f, fmaf(b.y, scls.y, sfts.y));
        float bz = fmaxf(0.f, fmaf(b.z, scls.z, sfts.z));
        float bw = fmaxf(0.f, fmaf(b.w, scls.w, sfts.w));
        float sx = fmaxf(0.f, ax+bx), sy = fmaxf(0.f, ay+by);
        float sz = fmaxf(0.f, az+bz), sw = fmaxf(0.f, aw+bw);
        float4 wc = ld4(Wc + c4);
        partial = sx*wc.x + sy*wc.y + sz*wc.z + sw*wc.w;
    }
    partial += __shfl_xor(partial, 1);
    partial += __shfl_xor(partial, 2);
    partial += __shfl_xor(partial, 4);
    partial += __shfl_xor(partial, 8);
    __shared__ float red[32];
    if (l == 0){
        if (i < Ng) w[i] = partial;
        red[r] = (i < Ng) ? partial : 0.f;
        red[16+r] = (i < Ng) ? partial*partial : 0.f;
    }
    __syncthreads();
    if (t == 0){
        float s2=0.f,q2=0.f;
        #pragma unroll
        for (int j2=0;j2<16;j2++){ s2+=red[j2]; q2+=red[16+j2]; }
        atomicAdd(sum_w, s2); atomicAdd(sumsq_w, q2);
    }
}

// --------- scatter: A[j][k] += sigmoid(BN(w[pairs_in])), k-minor layout ---------
__global__ void __launch_bounds__(256) k_scatter(
    const int* __restrict__ pin, const int* __restrict__ pout,
    const float* __restrict__ w, const float* __restrict__ stats,
    const float* __restrict__ gamma_c, const float* __restrict__ beta_c,
    float* __restrict__ A, int P, int Ng)
{
    int p = blockIdx.x*256 + threadIdx.x;
    int k = blockIdx.y;
    if (p >= P) return;
    float invN = 1.0f/(float)Ng;
    float mu = stats[256]*invN;
    float var = stats[257]*invN - mu*mu;
    float sc = gamma_c[0]*rsqrtf(var+EPSV);
    float sh = beta_c[0] - mu*sc;
    size_t o = (size_t)k*P + p;
    int i = pin[o]; int j = pout[o];
    float z = fmaf(sc, w[i], sh);
    float att = 1.0f/(1.0f+__expf(-z));
    atomicAdd(&A[(size_t)j*ASTRIDE + k], att);
}

// --------- final: out[j,:] = x[j,:] * (b_inv + sum_k A[j][k] * W_inv[k,:]) ---------
// 64 j per block; A staged to LDS via contiguous float4; fully coalesced x/out.
__global__ void __launch_bounds__(256) k_final(
    const float* __restrict__ x, const float* __restrict__ A,
    const float* __restrict__ Winv, const float* __restrict__ binv,
    float* __restrict__ out, int Nx, int K)
{
    __shared__ float Wl[27*64];      // 6.75 KB  [k][c]
    __shared__ float bl[64];
    __shared__ float Al[64*36];      // 9.2 KB, stride 36 (16B-aligned, conflict-safe)
    int t = threadIdx.x;
    for (int idx = t; idx < 27*64/4; idx += 256)
        ((float4*)Wl)[idx] = ((const float4*)Winv)[idx];
    if (t < 64) bl[t] = binv[t];
    int j0 = blockIdx.x * 64;
    // stage A[j0..j0+63][0..27]: 64*7 = 448 float4, contiguous in global
    for (int idx = t; idx < 64*(ASTRIDE/4); idx += 256){
        int r = idx / (ASTRIDE/4);
        int c4 = idx % (ASTRIDE/4);
        float4 v = make_float4(0.f,0.f,0.f,0.f);
        if (j0 + r < Nx) v = ld4(A + (size_t)(j0+r)*ASTRIDE + c4*4);
        st4(&Al[r*36 + c4*4], v);
    }
    __syncthreads();

    int cc = (t & 15) * 4;           // c-chunk, fixed across q
    int jb = t >> 4;                 // 0..15
    float4 acc[4];
    float4 b4 = ld4(&bl[cc]);
    #pragma unroll
    for (int q=0;q<4;q++) acc[q] = b4;
    for (int k=0;k<K;k++){
        float4 wv = ld4(&Wl[k*64 + cc]);
        #pragma unroll
        for (int q=0;q<4;q++){
            float a = Al[(q*16 + jb)*36 + k];
            acc[q].x = fmaf(a, wv.x, acc[q].x);
            acc[q].y = fmaf(a, wv.y, acc[q].y);
            acc[q].z = fmaf(a, wv.z, acc[q].z);
            acc[q].w = fmaf(a, wv.w, acc[q].w);
        }
    }
    #pragma unroll
    for (int q=0;q<4;q++){
        int j = j0 + q*16 + jb;
        if (j < Nx){
            float4 xv = ld4(x + (size_t)j*CS + cc);
            st4(out + (size_t)j*CS + cc,
                make_float4(xv.x*acc[q].x, xv.y*acc[q].y, xv.z*acc[q].z, xv.w*acc[q].w));
        }
    }
}

extern "C" void kernel_launch(void* const* d_in, const int* in_sizes, int n_in,
                              void* d_out, int out_size, void* d_ws, size_t ws_size,
                              hipStream_t stream)
{
    const float* g        = (const float*)d_in[0];
    const float* x        = (const float*)d_in[1];
    const int*   down_idx = (const int*)d_in[2];
    const int*   pin      = (const int*)d_in[3];
    const int*   pout     = (const int*)d_in[4];
    const float* Wg       = (const float*)d_in[5];
    const float* Ws       = (const float*)d_in[6];
    const float* Wc       = (const float*)d_in[7];
    const float* Winv     = (const float*)d_in[8];
    const float* binv     = (const float*)d_in[9];
    const float* gamma_g  = (const float*)d_in[10];
    const float* beta_g   = (const float*)d_in[11];
    const float* gamma_s  = (const float*)d_in[12];
    const float* beta_s   = (const float*)d_in[13];
    const float* gamma_c  = (const float*)d_in[14];
    const float* beta_c   = (const float*)d_in[15];

    int Ng = in_sizes[0] / CG;       // 60000
    int Nx = in_sizes[1] / CS;       // 200000
    int K  = in_sizes[8] / CS;       // 27
    int P  = in_sizes[3] / K;        // 100000

    float* ws = (float*)d_ws;
    size_t offA     = 0;
    size_t offStats = (size_t)Nx * ASTRIDE;   // A: Nx*28 floats (j-major, k-minor)
    size_t offYg    = offStats + 512;
    size_t offYs    = offYg + (size_t)Ng*CN;
    size_t offW     = offYs + (size_t)Ng*CN;

    float* A     = ws + offA;
    float* stats = ws + offStats;
    float* Yg    = ws + offYg;
    float* Ys    = ws + offYs;
    float* wbuf  = ws + offW;

    hipMemsetAsync(A, 0, (offStats + 512) * sizeof(float), stream);

    int gb = (Ng + 63) / 64;
    k_gemm<CG,false><<<gb, 256, 0, stream>>>(g, nullptr, Wg, Yg, stats+0, stats+64, Ng);
    k_gemm<CS,true ><<<gb, 256, 0, stream>>>(x, down_idx, Ws, Ys, stats+128, stats+192, Ng);
    k_fuse<<<(Ng+15)/16, 256, 0, stream>>>(Yg, Ys, stats, gamma_g, beta_g,
                                           gamma_s, beta_s, Wc, wbuf,
                                           stats+256, stats+257, Ng);
    dim3 sgrid((P+255)/256, K);
    k_scatter<<<sgrid, 256, 0, stream>>>(pin, pout, wbuf, stats, gamma_c, beta_c, A, P, Ng);
    k_final<<<(Nx+63)/64, 256, 0, stream>>>(x, A, Winv, binv, (float*)d_out, Nx, K);
}